// Round 1
// baseline (18660.628 us; speedup 1.0000x reference)
//
#include <hip/hip_runtime.h>

#define Bsz 4096
#define Lsz 128
#define NI  127
#define SD  32
#define AD  8
#define XDm 9
#define LAT 64
#define HID 128
#define BT  16
#define THR 512

// ---------------- W2 repack: [128][576] -> [j][l][12] (16B-aligned rows of 9+3pad) ----------------
__global__ __launch_bounds__(256) void repack_w2(const float* __restrict__ W2, float* __restrict__ W2p){
  int idx = blockIdx.x*256 + threadIdx.x;
  if (idx >= HID*LAT*12) return;
  int x = idx % 12; int jl = idx / 12; int l = jl % LAT; int j = jl / LAT;
  W2p[idx] = (x < XDm) ? W2[j*(LAT*XDm) + l*XDm + x] : 0.f;
}

// ---------------- Natural cubic spline: Thomas solve per (b,channel), store interior 2nd derivs m ----------------
// m_ws layout [i][b][c], i=0..127 (m[0]=m[127]=0)
__global__ __launch_bounds__(256) void spline_kernel(const float* __restrict__ t,
                                                     const float* __restrict__ a,
                                                     float* __restrict__ m_ws){
  __shared__ float cp_s[126];
  if (threadIdx.x == 0){
    float c = 0.25f; cp_s[0] = c;
    for (int i=1;i<126;i++){ c = 1.0f/(4.0f - c); cp_s[i] = c; }
  }
  __syncthreads();
  int tid = blockIdx.x*256 + threadIdx.x;   // tid = b*9 + c, exactly 36864 threads
  int b = tid/XDm, c = tid%XDm;
  float dp[126];
  const float* tb = t + (size_t)b*Lsz;
  const float* ab = a + (size_t)b*Lsz*AD + (c-1);
  float x0 = (c==0)? tb[0] : ab[0];
  float x1 = (c==0)? tb[1] : ab[AD];
  for (int i=0;i<126;i++){
    float x2 = (c==0)? tb[i+2] : ab[(size_t)(i+2)*AD];
    float rhs = 6.0f*(x2 - 2.0f*x1 + x0);
    dp[i] = (i==0)? rhs*0.25f : (rhs - dp[i-1])*cp_s[i];
    x0 = x1; x1 = x2;
  }
  m_ws[tid] = 0.0f;                               // m[0]
  m_ws[(size_t)127*(Bsz*XDm) + tid] = 0.0f;       // m[127]
  float mn = 0.0f;
  for (int k=125;k>=0;k--){
    mn = dp[k] - cp_s[k]*mn;
    m_ws[(size_t)(k+1)*(Bsz*XDm) + tid] = mn;
  }
}

// ---------------- Persistent RK4 integrator: 1 block per 16 batch elems ----------------
__global__ __launch_bounds__(THR, 2) void cde_integrate(
    const float* __restrict__ s, const float* __restrict__ a, const float* __restrict__ t,
    const float* __restrict__ encW, const float* __restrict__ encb,
    const float* __restrict__ W1, const float* __restrict__ b1,
    const float* __restrict__ b2, const float* __restrict__ decW, const float* __restrict__ decb,
    const float* __restrict__ W2p, const float* __restrict__ m_ws,
    float* __restrict__ out)
{
  __shared__ float W1s[LAT][HID];      // 32KB, [k][j]
  __shared__ float hs[BT][HID+4];      // pad 132: breaks 4-way bank conflict on h reads
  __shared__ float zs[BT][LAT+4];      // pad 68
  __shared__ float dXs[5][BT][XDm];    // dX at u in {0,.25,.5,.75,1}
  __shared__ float dWs[LAT][SD];
  __shared__ float b1s[HID];
  __shared__ float b2s[LAT*XDm];
  __shared__ float dbs[SD];

  const int tid = threadIdx.x;
  const int b0 = blockIdx.x * BT;

  for (int i=tid;i<LAT*HID;i+=THR) ((float*)W1s)[i] = W1[i];
  for (int i=tid;i<LAT*SD;i+=THR)  ((float*)dWs)[i] = decW[i];
  if (tid < HID) b1s[tid] = b1[tid];
  for (int i=tid;i<LAT*XDm;i+=THR) b2s[i] = b2[i];
  if (tid < SD) dbs[tid] = decb[tid];

  // ---- encode z0 = [s(32), a(8), t(1)] @ encW + encb ----
  {
    const int bb = tid >> 5;
    const int l0 = tid & 31;
    const float* sb = s + (size_t)(b0+bb)*Lsz*SD;
    const float* ab = a + (size_t)(b0+bb)*Lsz*AD;
    const float tv = t[(size_t)(b0+bb)*Lsz];
    for (int li=l0; li<LAT; li+=32){
      float acc = encb[li];
      #pragma unroll
      for (int k=0;k<SD;k++) acc += sb[k]*encW[k*LAT+li];
      #pragma unroll
      for (int k=0;k<AD;k++) acc += ab[k]*encW[(SD+k)*LAT+li];
      acc += tv*encW[(SD+AD)*LAT+li];
      zs[bb][li] = acc;
    }
  }
  __syncthreads();

  // ---- decode out[:,0,:] ----
  {
    const int bb = tid >> 5; const int o = tid & 31;
    float acc = dbs[o];
    #pragma unroll 8
    for (int k=0;k<LAT;k++) acc += zs[bb][k]*dWs[k][o];
    out[((size_t)(b0+bb)*Lsz + 0)*SD + o] = acc;
  }

  // ---- per-thread ownership ----
  const int ol  = tid >> 3;   // l: 0..63   (GEMM2 + RK4 owner)
  const int obg = tid & 7;    // b-pair: obg, obg+8
  float zb0 = zs[obg][ol];
  float zb1 = zs[obg+8][ol];
  float ka0 = 0.f, ka1 = 0.f;

  const int jp = tid >> 3;    // GEMM1: j-pair 2jp,2jp+1
  const int bg = tid & 7;     // GEMM1: b-pair bg, bg+8

  for (int iv=0; iv<NI; iv++){
    // ---- precompute dX(u) for the 5 distinct u values of this interval ----
    for (int idx=tid; idx<5*BT*XDm; idx+=THR){
      int ui = idx/(BT*XDm); int r = idx%(BT*XDm); int bb = r/XDm; int x = r%XDm;
      float u = 0.25f*(float)ui;
      int gb = b0+bb;
      float m0 = m_ws[(size_t)iv    *(Bsz*XDm) + (size_t)gb*XDm + x];
      float m1 = m_ws[(size_t)(iv+1)*(Bsz*XDm) + (size_t)gb*XDm + x];
      float xd;
      if (x==0) xd = t[(size_t)gb*Lsz + iv+1] - t[(size_t)gb*Lsz + iv];
      else      xd = a[((size_t)gb*Lsz + iv+1)*AD + x-1] - a[((size_t)gb*Lsz + iv)*AD + x-1];
      float cb = xd - (2.f*m0 + m1)*(1.f/6.f);
      float cc = 0.5f*m0;
      float cd = (m1 - m0)*(1.f/6.f);
      dXs[ui][bb][x] = cb + (2.f*cc)*u + (3.f*cd)*(u*u);
    }

    auto stage = [&](int ui, int mode){
      __syncthreads();                       // zs (and dXs) ready; prev hs readers done
      // GEMM1: h = relu(z @ W1 + b1)
      {
        const int j0 = 2*jp;
        float acc00 = b1s[j0], acc10 = b1s[j0+1];
        float acc01 = acc00,  acc11 = acc10;
        #pragma unroll 8
        for (int k=0;k<LAT;k++){
          const float2 wv = *(const float2*)&W1s[k][j0];
          const float z0v = zs[bg][k];
          const float z1v = zs[bg+8][k];
          acc00 += wv.x*z0v; acc01 += wv.x*z1v;
          acc10 += wv.y*z0v; acc11 += wv.y*z1v;
        }
        hs[bg][j0]     = fmaxf(acc00, 0.f);
        hs[bg+8][j0]   = fmaxf(acc01, 0.f);
        hs[bg][j0+1]   = fmaxf(acc10, 0.f);
        hs[bg+8][j0+1] = fmaxf(acc11, 0.f);
      }
      __syncthreads();                       // hs ready
      // GEMM2 (+b2) then contract with dX
      float v0[XDm], v1[XDm];
      #pragma unroll
      for (int x=0;x<XDm;x++){ v0[x] = b2s[ol*XDm+x]; v1[x] = v0[x]; }
      #pragma unroll 4
      for (int j=0;j<HID;j++){
        const float4* wp = (const float4*)(W2p + ((size_t)j*LAT + ol)*12);
        float4 wa = wp[0], wb = wp[1], wc = wp[2];
        float h0 = hs[obg][j], h1 = hs[obg+8][j];
        v0[0]+=h0*wa.x; v0[1]+=h0*wa.y; v0[2]+=h0*wa.z; v0[3]+=h0*wa.w;
        v0[4]+=h0*wb.x; v0[5]+=h0*wb.y; v0[6]+=h0*wb.z; v0[7]+=h0*wb.w;
        v0[8]+=h0*wc.x;
        v1[0]+=h1*wa.x; v1[1]+=h1*wa.y; v1[2]+=h1*wa.z; v1[3]+=h1*wa.w;
        v1[4]+=h1*wb.x; v1[5]+=h1*wb.y; v1[6]+=h1*wb.z; v1[7]+=h1*wb.w;
        v1[8]+=h1*wc.x;
      }
      float dz0 = 0.f, dz1 = 0.f;
      #pragma unroll
      for (int x=0;x<XDm;x++){
        dz0 += v0[x]*dXs[ui][obg][x];
        dz1 += v1[x]*dXs[ui][obg+8][x];
      }
      // RK4 bookkeeping (h = 0.5)
      if (mode == 0){        ka0 = dz0;       ka1 = dz1;
        zs[obg][ol] = zb0 + 0.25f*dz0; zs[obg+8][ol] = zb1 + 0.25f*dz1;
      } else if (mode == 1){ ka0 += 2.f*dz0;  ka1 += 2.f*dz1;
        zs[obg][ol] = zb0 + 0.25f*dz0; zs[obg+8][ol] = zb1 + 0.25f*dz1;
      } else if (mode == 2){ ka0 += 2.f*dz0;  ka1 += 2.f*dz1;
        zs[obg][ol] = zb0 + 0.5f*dz0;  zs[obg+8][ol] = zb1 + 0.5f*dz1;
      } else {               ka0 += dz0;      ka1 += dz1;
        zb0 += (0.5f/6.f)*ka0; zb1 += (0.5f/6.f)*ka1;
        zs[obg][ol] = zb0; zs[obg+8][ol] = zb1;
      }
    };

    // substep 0 (u0=0):   u = {0, .25, .25, .5}
    stage(0,0); stage(1,1); stage(1,2); stage(2,3);
    // substep 1 (u0=0.5): u = {.5, .75, .75, 1.0}
    stage(2,0); stage(3,1); stage(3,2); stage(4,3);

    __syncthreads();   // final z in zs
    // ---- decode out[:, iv+1, :] ----
    {
      const int bb = tid >> 5; const int o = tid & 31;
      float acc = dbs[o];
      #pragma unroll 8
      for (int k=0;k<LAT;k++) acc += zs[bb][k]*dWs[k][o];
      out[((size_t)(b0+bb)*Lsz + (iv+1))*SD + o] = acc;
    }
  }
}

extern "C" void kernel_launch(void* const* d_in, const int* in_sizes, int n_in,
                              void* d_out, int out_size, void* d_ws, size_t ws_size,
                              hipStream_t stream){
  const float* s    = (const float*)d_in[0];
  const float* a    = (const float*)d_in[1];
  const float* t    = (const float*)d_in[2];
  const float* encW = (const float*)d_in[3];
  const float* encb = (const float*)d_in[4];
  const float* W1   = (const float*)d_in[5];
  const float* b1   = (const float*)d_in[6];
  const float* W2   = (const float*)d_in[7];
  const float* b2   = (const float*)d_in[8];
  const float* decW = (const float*)d_in[9];
  const float* decb = (const float*)d_in[10];
  float* out = (float*)d_out;
  float* ws  = (float*)d_ws;
  float* W2p  = ws;                        // 98,304 floats (384KB)
  float* m_ws = ws + HID*LAT*12;           // 128*4096*9 floats (18.9MB)

  hipLaunchKernelGGL(repack_w2, dim3((HID*LAT*12+255)/256), dim3(256), 0, stream, W2, W2p);
  hipLaunchKernelGGL(spline_kernel, dim3(Bsz*XDm/256), dim3(256), 0, stream, t, a, m_ws);
  hipLaunchKernelGGL(cde_integrate, dim3(Bsz/BT), dim3(THR), 0, stream,
                     s,a,t,encW,encb,W1,b1,b2,decW,decb,W2p,m_ws,out);
}